// Round 2
// baseline (211.276 us; speedup 1.0000x reference)
//
#include <hip/hip_runtime.h>

typedef __bf16 bf16x8 __attribute__((ext_vector_type(8)));
typedef float f32x4 __attribute__((ext_vector_type(4)));

__device__ __forceinline__ unsigned short f2bf(float f) {
  unsigned int u = __float_as_uint(f);
  u += 0x7FFFu + ((u >> 16) & 1u);      // RNE
  return (unsigned short)(u >> 16);
}
__device__ __forceinline__ float bf2f(unsigned short s) {
  return __uint_as_float(((unsigned int)s) << 16);
}

// ---------------- prep: x -> bf16, weights -> transposed bf16 ----------------
__global__ __launch_bounds__(256) void prep_kernel(
    const float* __restrict__ x, const float* __restrict__ W0,
    const float* __restrict__ Wq, const float* __restrict__ Wk,
    const float* __restrict__ Wv, const float* __restrict__ W1,
    unsigned short* __restrict__ xb, unsigned short* __restrict__ w0t,
    unsigned short* __restrict__ wqkvt, unsigned short* __restrict__ w1t)
{
  int idx = blockIdx.x * 256 + threadIdx.x;
  const int XB = 6400 * 256, W0T = 512 * 256, WQKV = 1536 * 512, W1T = 256 * 512;
  if (idx < XB) { xb[idx] = f2bf(x[idx]); return; }
  idx -= XB;
  if (idx < W0T) {                       // w0t[n][k] = W0[k][n], k<256, n<512
    int n = idx >> 8, k = idx & 255;
    w0t[idx] = f2bf(W0[k * 512 + n]); return;
  }
  idx -= W0T;
  if (idx < WQKV) {                      // wqkvt[n][k], n<1536, k<512
    int n = idx >> 9, k = idx & 511;
    float v = (n < 512) ? Wq[k * 512 + n]
            : (n < 1024) ? Wk[k * 512 + (n - 512)]
                         : Wv[k * 512 + (n - 1024)];
    wqkvt[idx] = f2bf(v); return;
  }
  idx -= WQKV;
  if (idx < W1T) {                       // w1t[n][k] = W1[k][n], k<512, n<256
    int n = idx >> 9, k = idx & 511;
    w1t[idx] = f2bf(W1[k * 256 + n]);
  }
}

// ---------------- generic MFMA GEMM: C = act(A @ Bt^T + bias) ----------------
// A: M x K bf16 row-major (lda), Bt: N x K bf16 row-major (ldb).
// One wave per block; wave computes a 64x64 tile via 4x4 16x16x32 fragments.
template<bool RELU, bool OUT_BF16>
__global__ __launch_bounds__(64) void gemm_mfma(
    const unsigned short* __restrict__ A, int lda,
    const unsigned short* __restrict__ Bt, int ldb,
    const float* __restrict__ bias,
    void* __restrict__ Cout, int ldc, int K)
{
  const int m0 = blockIdx.x * 64;
  const int n0 = blockIdx.y * 64;
  const int l  = threadIdx.x;
  const int lr = l & 15;
  const int kq = l >> 4;
  f32x4 acc[4][4];
#pragma unroll
  for (int i = 0; i < 4; i++)
#pragma unroll
    for (int j = 0; j < 4; j++) acc[i][j] = (f32x4){0.f, 0.f, 0.f, 0.f};

  const unsigned short* Ap = A  + (long)(m0 + lr) * lda + 8 * kq;
  const unsigned short* Bp = Bt + (long)(n0 + lr) * ldb + 8 * kq;

  for (int k0 = 0; k0 < K; k0 += 32) {
    bf16x8 af[4], bfr[4];
#pragma unroll
    for (int i = 0; i < 4; i++)
      af[i] = *(const bf16x8*)(Ap + (long)(16 * i) * lda + k0);
#pragma unroll
    for (int j = 0; j < 4; j++)
      bfr[j] = *(const bf16x8*)(Bp + (long)(16 * j) * ldb + k0);
#pragma unroll
    for (int i = 0; i < 4; i++)
#pragma unroll
      for (int j = 0; j < 4; j++)
        acc[i][j] = __builtin_amdgcn_mfma_f32_16x16x32_bf16(af[i], bfr[j], acc[i][j], 0, 0, 0);
  }

#pragma unroll
  for (int i = 0; i < 4; i++) {
#pragma unroll
    for (int j = 0; j < 4; j++) {
      int col = n0 + 16 * j + lr;
      float bv = bias ? bias[col] : 0.0f;
#pragma unroll
      for (int r = 0; r < 4; r++) {
        int row = m0 + 16 * i + 4 * kq + r;   // D: row=(l>>4)*4+r, col=l&15 (m89-verified)
        float v = acc[i][j][r] + bv;
        if (RELU) v = fmaxf(v, 0.0f);
        if (OUT_BF16) ((unsigned short*)Cout)[(long)row * ldc + col] = f2bf(v);
        else          ((float*)Cout)[(long)row * ldc + col] = v;
      }
    }
  }
}

// ---------------- banded gram as full per-batch gram: G[b] = qh kh^T * scale ----------------
// qkv rows: [qh(512) | kh(512) | vh(512)], stride 1536, rows padded to 6416.
__global__ __launch_bounds__(64) void gram_kernel(
    const unsigned short* __restrict__ qkv, float* __restrict__ G)
{
  const float scale = 0.044194173824159216f;   // 1/sqrt(512)
  const int it = blockIdx.x;    // 0..6  (i tile)
  const int b  = blockIdx.y;    // 0..63
  const int l = threadIdx.x, lr = l & 15, kq = l >> 4;
  const unsigned short* qrow = qkv + (long)(b * 100 + it * 16 + lr) * 1536 + 8 * kq;
  const unsigned short* krow = qkv + (long)(b * 100 + lr) * 1536 + 512 + 8 * kq;
  f32x4 acc[7];
#pragma unroll
  for (int j = 0; j < 7; j++) acc[j] = (f32x4){0.f, 0.f, 0.f, 0.f};
  for (int k0 = 0; k0 < 512; k0 += 32) {
    bf16x8 aq = *(const bf16x8*)(qrow + k0);
#pragma unroll
    for (int j = 0; j < 7; j++) {
      bf16x8 bk = *(const bf16x8*)(krow + (long)(j * 16) * 1536 + k0);
      acc[j] = __builtin_amdgcn_mfma_f32_16x16x32_bf16(aq, bk, acc[j], 0, 0, 0);
    }
  }
  float* Gb = G + (long)b * 10000;
#pragma unroll
  for (int j = 0; j < 7; j++) {
#pragma unroll
    for (int r = 0; r < 4; r++) {
      int i  = it * 16 + 4 * kq + r;
      int jj = j * 16 + lr;
      if (i < 100 && jj < 100) Gb[i * 100 + jj] = acc[j][r] * scale;
    }
  }
}

// ---------------- per-(b,s) attention: softmax window, alpha out, beta-weighted v sum ----------------
__global__ __launch_bounds__(256) void attn_kernel(
    const float* __restrict__ G,             // [64][100][100], scale applied
    const unsigned short* __restrict__ qkv,  // v at +1024, stride 1536
    float* __restrict__ alpha_out,           // [6400][33][33]
    unsigned short* __restrict__ outb)       // [6400][512] bf16
{
  const int blk = blockIdx.x;                // 0..6399
  const int b = blk / 100, s = blk % 100;
  __shared__ float dmat[33][36];
  __shared__ float rowmax[33], rowinv[33];
  __shared__ float beta[36];
  const int tid = threadIdx.x;
  const float* Gb = G + (long)b * 10000;

  // gather window; OOB entries are exact zeros (matches zero-padded x_nei)
  for (int t = tid; t < 1089; t += 256) {
    int dw = t / 33, du = t % 33;
    int i = s + 16 - dw, j = s + 16 - du;
    float v = 0.f;
    if ((unsigned)i < 100u && (unsigned)j < 100u) v = Gb[i * 100 + j];
    dmat[dw][du] = v;
  }
  __syncthreads();

  // per-row max and 1/sum(exp): 4 lanes per row
  if (tid < 132) {
    int row = tid >> 2, g = tid & 3;
    float m = -1e30f;
    for (int u = g; u < 33; u += 4) m = fmaxf(m, dmat[row][u]);
    m = fmaxf(m, __shfl_xor(m, 1));
    m = fmaxf(m, __shfl_xor(m, 2));
    float ssum = 0.f;
    for (int u = g; u < 33; u += 4) ssum += __expf(dmat[row][u] - m);
    ssum += __shfl_xor(ssum, 1);
    ssum += __shfl_xor(ssum, 2);
    if (g == 0) { rowmax[row] = m; rowinv[row] = 1.0f / ssum; }
  }
  __syncthreads();

  // alpha: write out + keep in LDS for beta
  float* aout = alpha_out + (long)blk * 1089;
  for (int t = tid; t < 1089; t += 256) {
    int dw = t / 33, du = t % 33;
    float a = __expf(dmat[dw][du] - rowmax[dw]) * rowinv[dw];
    aout[t] = a;
    dmat[dw][du] = a;
  }
  __syncthreads();

  // beta[u] = sum_w alpha[w][u]
  if (tid < 33) {
    float sum = 0.f;
    for (int w = 0; w < 33; ++w) sum += dmat[w][tid];
    beta[tid] = sum;
  }
  __syncthreads();

  // out[b,s,:] = sum_u beta[u] * vh[b, s+16-u, :]
  const unsigned short* vbase = qkv + (long)(b * 100) * 1536 + 1024;
  {
    int c = tid;
    float acc0 = 0.f, acc1 = 0.f;
    for (int u = 0; u < 33; ++u) {
      int p = s + 16 - u;
      if ((unsigned)p < 100u) {
        float bw = beta[u];
        const unsigned short* vr = vbase + (long)p * 1536;
        acc0 += bw * bf2f(vr[c]);
        acc1 += bw * bf2f(vr[c + 256]);
      }
    }
    unsigned short* orow = outb + (long)blk * 512;
    orow[c]       = f2bf(acc0);
    orow[c + 256] = f2bf(acc1);
  }
}

extern "C" void kernel_launch(void* const* d_in, const int* in_sizes, int n_in,
                              void* d_out, int out_size, void* d_ws, size_t ws_size,
                              hipStream_t stream) {
  const float* x  = (const float*)d_in[0];
  const float* W0 = (const float*)d_in[1];
  const float* b0 = (const float*)d_in[2];
  const float* Wq = (const float*)d_in[3];
  const float* Wk = (const float*)d_in[4];
  const float* Wv = (const float*)d_in[5];
  const float* W1 = (const float*)d_in[6];
  const float* b1 = (const float*)d_in[7];

  char* ws = (char*)d_ws;
  unsigned short* xb    = (unsigned short*)(ws + 0);         // 6400x256 bf16
  unsigned short* w0t   = (unsigned short*)(ws + 3276800);   // 512x256
  unsigned short* wqkvt = (unsigned short*)(ws + 3538944);   // 1536x512
  unsigned short* w1t   = (unsigned short*)(ws + 5111808);   // 256x512
  unsigned short* h     = (unsigned short*)(ws + 5373952);   // 6400x512
  unsigned short* qkv   = (unsigned short*)(ws + 11927552);  // 6416x1536 (16 pad rows)
  float*          G     = (float*)(ws + 31637504);           // 64x100x100 f32
  unsigned short* outb  = (unsigned short*)(ws + 34197504);  // 6400x512
  // total ws use: 40,751,104 bytes

  float* y_out     = (float*)d_out;            // 6400x256 f32
  float* alpha_out = y_out + 6400 * 256;       // 6400x33x33 f32

  prep_kernel<<<10496, 256, 0, stream>>>(x, W0, Wq, Wk, Wv, W1, xb, w0t, wqkvt, w1t);
  // h = relu(x @ W0 + b0)
  gemm_mfma<true,  true ><<<dim3(100, 8),  64, 0, stream>>>(xb, 256, w0t, 256, b0, h, 512, 256);
  // [qh|kh|vh] = h @ [Wq|Wk|Wv]
  gemm_mfma<false, true ><<<dim3(100, 24), 64, 0, stream>>>(h, 512, wqkvt, 512, nullptr, qkv, 1536, 512);
  // G[b] = qh kh^T / sqrt(512)
  gram_kernel<<<dim3(7, 64), 64, 0, stream>>>(qkv, G);
  // softmax windows -> alpha, beta-weighted v -> outb
  attn_kernel<<<6400, 256, 0, stream>>>(G, qkv, alpha_out, outb);
  // y = relu(outb @ W1 + b1)
  gemm_mfma<true,  false><<<dim3(100, 4), 64, 0, stream>>>(outb, 512, w1t, 512, b1, y_out, 256, 512);
}

// Round 3
// 178.215 us; speedup vs baseline: 1.1855x; 1.1855x over previous
//
#include <hip/hip_runtime.h>

typedef __bf16 bf16x8 __attribute__((ext_vector_type(8)));
typedef float f32x4 __attribute__((ext_vector_type(4)));
typedef unsigned int u32;

__device__ __forceinline__ unsigned short f2bf(float f) {
  unsigned int u = __float_as_uint(f);
  u += 0x7FFFu + ((u >> 16) & 1u);      // RNE
  return (unsigned short)(u >> 16);
}
__device__ __forceinline__ float bf2f(unsigned short s) {
  return __uint_as_float(((unsigned int)s) << 16);
}

// async global->LDS, 16B per lane (dest = wave-uniform base + lane*16)
__device__ __forceinline__ void gload16(const void* g, void* l) {
  __builtin_amdgcn_global_load_lds(
      (const __attribute__((address_space(1))) u32*)g,
      (__attribute__((address_space(3))) u32*)l, 16, 0, 0);
}

// ---------------- prep: vectorized x->bf16; LDS-tiled 32x32 transposes ----------------
// grid: [0,1600) x convert; [1600,1600+1024) weight transpose tiles
__global__ __launch_bounds__(256) void prep_kernel(
    const float* __restrict__ x, const float* __restrict__ W0,
    const float* __restrict__ Wq, const float* __restrict__ Wk,
    const float* __restrict__ Wv, const float* __restrict__ W1,
    unsigned short* __restrict__ xb, unsigned short* __restrict__ w0t,
    unsigned short* __restrict__ wqkvt, unsigned short* __restrict__ w1t)
{
  __shared__ float tile[32][33];
  const int bid = blockIdx.x, tid = threadIdx.x;
  if (bid < 1600) {                      // x: 6400*256 floats, 4/thread
    long i = (long)bid * 1024 + tid * 4;
    float4 v = *(const float4*)(x + i);
    unsigned short o0 = f2bf(v.x), o1 = f2bf(v.y), o2 = f2bf(v.z), o3 = f2bf(v.w);
    ushort4 o = {o0, o1, o2, o3};
    *(ushort4*)(xb + i) = o;
    return;
  }
  int id = bid - 1600;                   // 0..1023 transpose tiles
  const float* src; unsigned short* dst;
  int N, DLD, k0, n0, drow0;
  if (id < 128) {                        // W0 (256x512) -> w0t[512][256]
    src = W0; N = 512; dst = w0t; DLD = 256;
    k0 = (id >> 4) * 32; n0 = (id & 15) * 32; drow0 = n0;
  } else if (id < 896) {                 // Wq/Wk/Wv (512x512) -> wqkvt[1536][512]
    int id1 = id - 128, which = id1 >> 8, rem = id1 & 255;
    src = (which == 0) ? Wq : (which == 1) ? Wk : Wv;
    N = 512; dst = wqkvt; DLD = 512;
    k0 = (rem >> 4) * 32; n0 = (rem & 15) * 32; drow0 = which * 512 + n0;
  } else {                               // W1 (512x256) -> w1t[256][512]
    int id2 = id - 896;
    src = W1; N = 256; dst = w1t; DLD = 512;
    k0 = (id2 >> 3) * 32; n0 = (id2 & 7) * 32; drow0 = n0;
  }
  const int tr = tid >> 5, tc = tid & 31;
#pragma unroll
  for (int rr = 0; rr < 4; ++rr) {
    int kl = tr + rr * 8;
    tile[kl][tc] = src[(long)(k0 + kl) * N + n0 + tc];
  }
  __syncthreads();
#pragma unroll
  for (int rr = 0; rr < 4; ++rr) {
    int nl = tr + rr * 8;
    dst[(long)(drow0 + nl) * DLD + k0 + tc] = f2bf(tile[tc][nl]);
  }
}

// ---------------- 4-wave MFMA GEMM: C = act(A @ Bt^T + bias) ----------------
// Tile 64(M) x 128(N), BK=32, double-buffered LDS via global_load_lds width-16.
// Wave w computes rows m0..m0+63, cols n0+w*32..+32 (4x2 16x16 frags).
template<bool RELU, bool OUT_BF16>
__global__ __launch_bounds__(256) void gemm_tile(
    const unsigned short* __restrict__ A, int lda,
    const unsigned short* __restrict__ Bt, int ldb,
    const float* __restrict__ bias,
    void* __restrict__ Cout, int ldc, int KT)    // K = KT*32
{
  __shared__ unsigned short As[2][64 * 32];      // 4KB each buf
  __shared__ unsigned short Bs[2][128 * 32];     // 8KB each buf
  const int tid = threadIdx.x;
  const int m0 = blockIdx.x * 64;
  const int n0 = blockIdx.y * 128;
  const int w = tid >> 6, lane = tid & 63;
  const int lr = lane & 15, kq = lane >> 4;

  // staging sources: chunk c -> row c>>2, kchunk c&3 (8 bf16 = 16B)
  const unsigned short* Ag  = A  + (long)(m0 + (tid >> 2)) * lda + (tid & 3) * 8;
  const unsigned short* Bg0 = Bt + (long)(n0 + (tid >> 2)) * ldb + (tid & 3) * 8;
  const unsigned short* Bg1 = Bg0 + (long)64 * ldb;

  f32x4 acc[4][2];
#pragma unroll
  for (int i = 0; i < 4; i++)
#pragma unroll
    for (int j = 0; j < 2; j++) acc[i][j] = (f32x4){0.f, 0.f, 0.f, 0.f};

#define STAGE(buf, kt) do { int ko = (kt) * 32;                      \
    gload16(Ag + ko,  &As[buf][tid * 8]);                            \
    gload16(Bg0 + ko, &Bs[buf][tid * 8]);                            \
    gload16(Bg1 + ko, &Bs[buf][(tid + 256) * 8]); } while (0)

  STAGE(0, 0);
  __syncthreads();
  int cur = 0;
  for (int kt = 0; kt < KT; ++kt) {
    if (kt + 1 < KT) STAGE(cur ^ 1, kt + 1);
    bf16x8 af[4], bfr[2];
#pragma unroll
    for (int ii = 0; ii < 4; ii++)
      af[ii] = *(const bf16x8*)&As[cur][(16 * ii + lr) * 32 + 8 * kq];
#pragma unroll
    for (int jj = 0; jj < 2; jj++)
      bfr[jj] = *(const bf16x8*)&Bs[cur][(w * 32 + 16 * jj + lr) * 32 + 8 * kq];
#pragma unroll
    for (int ii = 0; ii < 4; ii++)
#pragma unroll
      for (int jj = 0; jj < 2; jj++)
        acc[ii][jj] = __builtin_amdgcn_mfma_f32_16x16x32_bf16(af[ii], bfr[jj], acc[ii][jj], 0, 0, 0);
    __syncthreads();
    cur ^= 1;
  }
#undef STAGE

#pragma unroll
  for (int ii = 0; ii < 4; ii++) {
#pragma unroll
    for (int jj = 0; jj < 2; jj++) {
      int col = n0 + w * 32 + 16 * jj + lr;
      float bv = bias ? bias[col] : 0.0f;
#pragma unroll
      for (int r = 0; r < 4; r++) {
        int row = m0 + 16 * ii + 4 * kq + r;     // D: row=(l>>4)*4+r, col=l&15
        float v = acc[ii][jj][r] + bv;
        if (RELU) v = fmaxf(v, 0.0f);
        if (OUT_BF16) ((unsigned short*)Cout)[(long)row * ldc + col] = f2bf(v);
        else          ((float*)Cout)[(long)row * ldc + col] = v;
      }
    }
  }
}

// ---------------- batched gram: G[b] = qh_b kh_b^T * scale (same tile structure) ----------------
// blockIdx.x = m-tile (0/1), blockIdx.y = batch. Tile 64x128 covers 100x100 masked.
__global__ __launch_bounds__(256) void gram_tile(
    const unsigned short* __restrict__ qkv, float* __restrict__ G)
{
  const float scale = 0.044194173824159216f;     // 1/sqrt(512)
  __shared__ unsigned short As[2][64 * 32];
  __shared__ unsigned short Bs[2][128 * 32];
  const int tid = threadIdx.x;
  const int m0 = blockIdx.x * 64;
  const int b  = blockIdx.y;
  const int w = tid >> 6, lane = tid & 63;
  const int lr = lane & 15, kq = lane >> 4;

  const unsigned short* A  = qkv + (long)b * 100 * 1536;        // qh rows
  const unsigned short* Bt = A + 512;                           // kh rows
  const unsigned short* Ag  = A  + (long)(m0 + (tid >> 2)) * 1536 + (tid & 3) * 8;
  const unsigned short* Bg0 = Bt + (long)(tid >> 2) * 1536 + (tid & 3) * 8;
  const unsigned short* Bg1 = Bg0 + (long)64 * 1536;

  f32x4 acc[4][2];
#pragma unroll
  for (int i = 0; i < 4; i++)
#pragma unroll
    for (int j = 0; j < 2; j++) acc[i][j] = (f32x4){0.f, 0.f, 0.f, 0.f};

#define STAGE(buf, kt) do { int ko = (kt) * 32;                      \
    gload16(Ag + ko,  &As[buf][tid * 8]);                            \
    gload16(Bg0 + ko, &Bs[buf][tid * 8]);                            \
    gload16(Bg1 + ko, &Bs[buf][(tid + 256) * 8]); } while (0)

  STAGE(0, 0);
  __syncthreads();
  int cur = 0;
  for (int kt = 0; kt < 16; ++kt) {
    if (kt + 1 < 16) STAGE(cur ^ 1, kt + 1);
    bf16x8 af[4], bfr[2];
#pragma unroll
    for (int ii = 0; ii < 4; ii++)
      af[ii] = *(const bf16x8*)&As[cur][(16 * ii + lr) * 32 + 8 * kq];
#pragma unroll
    for (int jj = 0; jj < 2; jj++)
      bfr[jj] = *(const bf16x8*)&Bs[cur][(w * 32 + 16 * jj + lr) * 32 + 8 * kq];
#pragma unroll
    for (int ii = 0; ii < 4; ii++)
#pragma unroll
      for (int jj = 0; jj < 2; jj++)
        acc[ii][jj] = __builtin_amdgcn_mfma_f32_16x16x32_bf16(af[ii], bfr[jj], acc[ii][jj], 0, 0, 0);
    __syncthreads();
    cur ^= 1;
  }
#undef STAGE

  float* Gb = G + (long)b * 10000;
#pragma unroll
  for (int ii = 0; ii < 4; ii++) {
#pragma unroll
    for (int jj = 0; jj < 2; jj++) {
      int j = w * 32 + 16 * jj + lr;
#pragma unroll
      for (int r = 0; r < 4; r++) {
        int i = m0 + 16 * ii + 4 * kq + r;
        if (i < 100 && j < 100) Gb[i * 100 + j] = acc[ii][jj][r] * scale;
      }
    }
  }
}

// ---------------- per-(b,s) attention: softmax window, alpha out, beta-weighted v sum ----------------
__global__ __launch_bounds__(256) void attn_kernel(
    const float* __restrict__ G,             // [64][100][100], scale applied
    const unsigned short* __restrict__ qkv,  // v at +1024, stride 1536
    float* __restrict__ alpha_out,           // [6400][33][33]
    unsigned short* __restrict__ outb)       // [6400][512] bf16
{
  const int blk = blockIdx.x;                // 0..6399
  const int b = blk / 100, s = blk % 100;
  __shared__ float dmat[33][36];
  __shared__ float rowmax[33], rowinv[33];
  __shared__ float beta[36];
  const int tid = threadIdx.x;
  const float* Gb = G + (long)b * 10000;

  for (int t = tid; t < 1089; t += 256) {
    int dw = t / 33, du = t % 33;
    int i = s + 16 - dw, j = s + 16 - du;
    float v = 0.f;
    if ((unsigned)i < 100u && (unsigned)j < 100u) v = Gb[i * 100 + j];
    dmat[dw][du] = v;
  }
  __syncthreads();

  if (tid < 132) {
    int row = tid >> 2, g = tid & 3;
    float m = -1e30f;
    for (int u = g; u < 33; u += 4) m = fmaxf(m, dmat[row][u]);
    m = fmaxf(m, __shfl_xor(m, 1));
    m = fmaxf(m, __shfl_xor(m, 2));
    float ssum = 0.f;
    for (int u = g; u < 33; u += 4) ssum += __expf(dmat[row][u] - m);
    ssum += __shfl_xor(ssum, 1);
    ssum += __shfl_xor(ssum, 2);
    if (g == 0) { rowmax[row] = m; rowinv[row] = 1.0f / ssum; }
  }
  __syncthreads();

  float* aout = alpha_out + (long)blk * 1089;
  for (int t = tid; t < 1089; t += 256) {
    int dw = t / 33, du = t % 33;
    float a = __expf(dmat[dw][du] - rowmax[dw]) * rowinv[dw];
    aout[t] = a;
    dmat[dw][du] = a;
  }
  __syncthreads();

  if (tid < 33) {
    float sum = 0.f;
    for (int w = 0; w < 33; ++w) sum += dmat[w][tid];
    beta[tid] = sum;
  }
  __syncthreads();

  const unsigned short* vbase = qkv + (long)(b * 100) * 1536 + 1024;
  {
    int c = tid;
    float acc0 = 0.f, acc1 = 0.f;
    for (int u = 0; u < 33; ++u) {
      int p = s + 16 - u;
      if ((unsigned)p < 100u) {
        float bw = beta[u];
        const unsigned short* vr = vbase + (long)p * 1536;
        acc0 += bw * bf2f(vr[c]);
        acc1 += bw * bf2f(vr[c + 256]);
      }
    }
    unsigned short* orow = outb + (long)blk * 512;
    orow[c]       = f2bf(acc0);
    orow[c + 256] = f2bf(acc1);
  }
}

extern "C" void kernel_launch(void* const* d_in, const int* in_sizes, int n_in,
                              void* d_out, int out_size, void* d_ws, size_t ws_size,
                              hipStream_t stream) {
  const float* x  = (const float*)d_in[0];
  const float* W0 = (const float*)d_in[1];
  const float* b0 = (const float*)d_in[2];
  const float* Wq = (const float*)d_in[3];
  const float* Wk = (const float*)d_in[4];
  const float* Wv = (const float*)d_in[5];
  const float* W1 = (const float*)d_in[6];
  const float* b1 = (const float*)d_in[7];

  char* ws = (char*)d_ws;
  unsigned short* xb    = (unsigned short*)(ws + 0);         // 6400x256 bf16
  unsigned short* w0t   = (unsigned short*)(ws + 3276800);   // 512x256
  unsigned short* wqkvt = (unsigned short*)(ws + 3538944);   // 1536x512
  unsigned short* w1t   = (unsigned short*)(ws + 5111808);   // 256x512
  unsigned short* h     = (unsigned short*)(ws + 5373952);   // 6400x512
  unsigned short* qkv   = (unsigned short*)(ws + 11927552);  // 6432x1536 (32 pad rows)
  float*          G     = (float*)(ws + 31686656);           // 64x100x100 f32
  unsigned short* outb  = (unsigned short*)(ws + 34246656);  // 6400x512
  // total ws use: 40,800,256 bytes

  float* y_out     = (float*)d_out;            // 6400x256 f32
  float* alpha_out = y_out + 6400 * 256;       // 6400x33x33 f32

  prep_kernel<<<2624, 256, 0, stream>>>(x, W0, Wq, Wk, Wv, W1, xb, w0t, wqkvt, w1t);
  // h = relu(x @ W0 + b0): M=6400, N=512, K=256
  gemm_tile<true,  true ><<<dim3(100, 4),  256, 0, stream>>>(xb, 256, w0t, 256, b0, h, 512, 8);
  // [qh|kh|vh] = h @ [Wq|Wk|Wv]: M=6400, N=1536, K=512
  gemm_tile<false, true ><<<dim3(100, 12), 256, 0, stream>>>(h, 512, wqkvt, 512, nullptr, qkv, 1536, 16);
  // G[b] = qh kh^T / sqrt(512)
  gram_tile<<<dim3(2, 64), 256, 0, stream>>>(qkv, G);
  // softmax windows -> alpha, beta-weighted v -> outb
  attn_kernel<<<6400, 256, 0, stream>>>(G, qkv, alpha_out, outb);
  // y = relu(outb @ W1 + b1): M=6400, N=256, K=512
  gemm_tile<true,  false><<<dim3(100, 2),  256, 0, stream>>>(outb, 512, w1t, 512, b1, y_out, 256, 16);
}

// Round 4
// 176.502 us; speedup vs baseline: 1.1970x; 1.0097x over previous
//
#include <hip/hip_runtime.h>

typedef __bf16 bf16x8 __attribute__((ext_vector_type(8)));
typedef float f32x4 __attribute__((ext_vector_type(4)));
typedef unsigned int u32;

__device__ __forceinline__ unsigned short f2bf(float f) {
  unsigned int u = __float_as_uint(f);
  u += 0x7FFFu + ((u >> 16) & 1u);      // RNE
  return (unsigned short)(u >> 16);
}
__device__ __forceinline__ float bf2f(unsigned short s) {
  return __uint_as_float(((unsigned int)s) << 16);
}

// async global->LDS, 16B per lane (dest = wave-uniform base + lane*16)
__device__ __forceinline__ void gload16(const void* g, void* l) {
  __builtin_amdgcn_global_load_lds(
      (const __attribute__((address_space(1))) u32*)g,
      (__attribute__((address_space(3))) u32*)l, 16, 0, 0);
}

// ---------------- prep: vectorized x->bf16; LDS-tiled 32x32 transposes ----------------
__global__ __launch_bounds__(256) void prep_kernel(
    const float* __restrict__ x, const float* __restrict__ W0,
    const float* __restrict__ Wq, const float* __restrict__ Wk,
    const float* __restrict__ Wv, const float* __restrict__ W1,
    unsigned short* __restrict__ xb, unsigned short* __restrict__ w0t,
    unsigned short* __restrict__ wqkvt, unsigned short* __restrict__ w1t)
{
  __shared__ float tile[32][33];
  const int bid = blockIdx.x, tid = threadIdx.x;
  if (bid < 1600) {                      // x: 6400*256 floats, 4/thread
    long i = (long)bid * 1024 + tid * 4;
    float4 v = *(const float4*)(x + i);
    ushort4 o = {f2bf(v.x), f2bf(v.y), f2bf(v.z), f2bf(v.w)};
    *(ushort4*)(xb + i) = o;
    return;
  }
  int id = bid - 1600;                   // 0..1023 transpose tiles
  const float* src; unsigned short* dst;
  int N, DLD, k0, n0, drow0;
  if (id < 128) {                        // W0 (256x512) -> w0t[512][256]
    src = W0; N = 512; dst = w0t; DLD = 256;
    k0 = (id >> 4) * 32; n0 = (id & 15) * 32; drow0 = n0;
  } else if (id < 896) {                 // Wq/Wk/Wv (512x512) -> wqkvt[1536][512]
    int id1 = id - 128, which = id1 >> 8, rem = id1 & 255;
    src = (which == 0) ? Wq : (which == 1) ? Wk : Wv;
    N = 512; dst = wqkvt; DLD = 512;
    k0 = (rem >> 4) * 32; n0 = (rem & 15) * 32; drow0 = which * 512 + n0;
  } else {                               // W1 (512x256) -> w1t[256][512]
    int id2 = id - 896;
    src = W1; N = 256; dst = w1t; DLD = 512;
    k0 = (id2 >> 3) * 32; n0 = (id2 & 7) * 32; drow0 = n0;
  }
  const int tr = tid >> 5, tc = tid & 31;
#pragma unroll
  for (int rr = 0; rr < 4; ++rr) {
    int kl = tr + rr * 8;
    tile[kl][tc] = src[(long)(k0 + kl) * N + n0 + tc];
  }
  __syncthreads();
#pragma unroll
  for (int rr = 0; rr < 4; ++rr) {
    int nl = tr + rr * 8;
    dst[(long)(drow0 + nl) * DLD + k0 + tc] = f2bf(tile[tc][nl]);
  }
}

// ---------------- 4-wave MFMA GEMM, 64x128 tile, BK=32, swizzled LDS ----------------
// LDS slot (r, c_l) holds global k-chunk c_g = c_l ^ ((r>>1)&3)  (involution).
// Read of chunk (row,kq) -> slot kq ^ ((row>>1)&3); for all fragment rows
// (row>>1)&3 == (lr>>1)&3, so kqs is per-lane constant. 2-way banks (free).
template<bool RELU, bool OUT_BF16>
__global__ __launch_bounds__(256) void gemm_tile(
    const unsigned short* __restrict__ A, int lda,
    const unsigned short* __restrict__ Bt, int ldb,
    const float* __restrict__ bias,
    void* __restrict__ Cout, int ldc, int KT)    // K = KT*32
{
  __shared__ unsigned short As[2][64 * 32];
  __shared__ unsigned short Bs[2][128 * 32];
  const int tid = threadIdx.x;
  const int m0 = blockIdx.x * 64;
  const int n0 = blockIdx.y * 128;
  const int w = tid >> 6, lane = tid & 63;
  const int lr = lane & 15, kq = lane >> 4;
  const int cg  = (tid & 3) ^ ((tid >> 3) & 3);       // swizzled source chunk
  const int kqs = kq ^ ((lr >> 1) & 3);               // swizzled read slot

  const unsigned short* Ag  = A  + (long)(m0 + (tid >> 2)) * lda + cg * 8;
  const unsigned short* Bg0 = Bt + (long)(n0 + (tid >> 2)) * ldb + cg * 8;
  const unsigned short* Bg1 = Bg0 + (long)64 * ldb;   // rows+64: (r>>1)&3 unchanged

  f32x4 acc[4][2];
#pragma unroll
  for (int i = 0; i < 4; i++)
#pragma unroll
    for (int j = 0; j < 2; j++) acc[i][j] = (f32x4){0.f, 0.f, 0.f, 0.f};

#define STAGE(buf, kt) do { int ko = (kt) * 32;                      \
    gload16(Ag + ko,  &As[buf][tid * 8]);                            \
    gload16(Bg0 + ko, &Bs[buf][tid * 8]);                            \
    gload16(Bg1 + ko, &Bs[buf][(tid + 256) * 8]); } while (0)

  STAGE(0, 0);
  __syncthreads();
  int cur = 0;
  for (int kt = 0; kt < KT; ++kt) {
    if (kt + 1 < KT) STAGE(cur ^ 1, kt + 1);
    bf16x8 af[4], bfr[2];
#pragma unroll
    for (int ii = 0; ii < 4; ii++)
      af[ii] = *(const bf16x8*)&As[cur][(16 * ii + lr) * 32 + 8 * kqs];
#pragma unroll
    for (int jj = 0; jj < 2; jj++)
      bfr[jj] = *(const bf16x8*)&Bs[cur][(w * 32 + 16 * jj + lr) * 32 + 8 * kqs];
#pragma unroll
    for (int ii = 0; ii < 4; ii++)
#pragma unroll
      for (int jj = 0; jj < 2; jj++)
        acc[ii][jj] = __builtin_amdgcn_mfma_f32_16x16x32_bf16(af[ii], bfr[jj], acc[ii][jj], 0, 0, 0);
    __syncthreads();
    cur ^= 1;
  }
#undef STAGE

#pragma unroll
  for (int ii = 0; ii < 4; ii++) {
#pragma unroll
    for (int jj = 0; jj < 2; jj++) {
      int col = n0 + w * 32 + 16 * jj + lr;
      float bv = bias ? bias[col] : 0.0f;
#pragma unroll
      for (int r = 0; r < 4; r++) {
        int row = m0 + 16 * ii + 4 * kq + r;     // D: row=(l>>4)*4+r, col=l&15
        float v = acc[ii][jj][r] + bv;
        if (RELU) v = fmaxf(v, 0.0f);
        if (OUT_BF16) ((unsigned short*)Cout)[(long)row * ldc + col] = f2bf(v);
        else          ((float*)Cout)[(long)row * ldc + col] = v;
      }
    }
  }
}

// ---------------- batched gram: G[b] = qh_b kh_b^T * scale (swizzled LDS) ----------------
__global__ __launch_bounds__(256) void gram_tile(
    const unsigned short* __restrict__ qkv, float* __restrict__ G)
{
  const float scale = 0.044194173824159216f;     // 1/sqrt(512)
  __shared__ unsigned short As[2][64 * 32];
  __shared__ unsigned short Bs[2][128 * 32];
  const int tid = threadIdx.x;
  const int m0 = blockIdx.x * 64;
  const int b  = blockIdx.y;
  const int w = tid >> 6, lane = tid & 63;
  const int lr = lane & 15, kq = lane >> 4;
  const int cg  = (tid & 3) ^ ((tid >> 3) & 3);
  const int kqs = kq ^ ((lr >> 1) & 3);

  const unsigned short* A  = qkv + (long)b * 100 * 1536;        // qh rows
  const unsigned short* Bt = A + 512;                           // kh rows
  const unsigned short* Ag  = A  + (long)(m0 + (tid >> 2)) * 1536 + cg * 8;
  const unsigned short* Bg0 = Bt + (long)(tid >> 2) * 1536 + cg * 8;
  const unsigned short* Bg1 = Bg0 + (long)64 * 1536;

  f32x4 acc[4][2];
#pragma unroll
  for (int i = 0; i < 4; i++)
#pragma unroll
    for (int j = 0; j < 2; j++) acc[i][j] = (f32x4){0.f, 0.f, 0.f, 0.f};

#define STAGE(buf, kt) do { int ko = (kt) * 32;                      \
    gload16(Ag + ko,  &As[buf][tid * 8]);                            \
    gload16(Bg0 + ko, &Bs[buf][tid * 8]);                            \
    gload16(Bg1 + ko, &Bs[buf][(tid + 256) * 8]); } while (0)

  STAGE(0, 0);
  __syncthreads();
  int cur = 0;
  for (int kt = 0; kt < 16; ++kt) {
    if (kt + 1 < 16) STAGE(cur ^ 1, kt + 1);
    bf16x8 af[4], bfr[2];
#pragma unroll
    for (int ii = 0; ii < 4; ii++)
      af[ii] = *(const bf16x8*)&As[cur][(16 * ii + lr) * 32 + 8 * kqs];
#pragma unroll
    for (int jj = 0; jj < 2; jj++)
      bfr[jj] = *(const bf16x8*)&Bs[cur][(w * 32 + 16 * jj + lr) * 32 + 8 * kqs];
#pragma unroll
    for (int ii = 0; ii < 4; ii++)
#pragma unroll
      for (int jj = 0; jj < 2; jj++)
        acc[ii][jj] = __builtin_amdgcn_mfma_f32_16x16x32_bf16(af[ii], bfr[jj], acc[ii][jj], 0, 0, 0);
    __syncthreads();
    cur ^= 1;
  }
#undef STAGE

  float* Gb = G + (long)b * 10000;
#pragma unroll
  for (int ii = 0; ii < 4; ii++) {
#pragma unroll
    for (int jj = 0; jj < 2; jj++) {
      int j = w * 32 + 16 * jj + lr;
#pragma unroll
      for (int r = 0; r < 4; r++) {
        int i = m0 + 16 * ii + 4 * kq + r;
        if (i < 100 && j < 100) Gb[i * 100 + j] = acc[ii][jj][r] * scale;
      }
    }
  }
}

// ---------------- per-(b,s) attention: no-max softmax (|d|<~4), fused exp gather ----------------
__global__ __launch_bounds__(256) void attn_kernel(
    const float* __restrict__ G,             // [64][100][100], scale applied
    const unsigned short* __restrict__ qkv,  // v at +1024, stride 1536
    float* __restrict__ alpha_out,           // [6400][33][33]
    unsigned short* __restrict__ outb)       // [6400][512] bf16
{
  const int blk = blockIdx.x;                // 0..6399
  const int b = blk / 100, s = blk % 100;
  __shared__ float dmat[33][36];
  __shared__ float rowinv[33];
  __shared__ float beta[36];
  const int tid = threadIdx.x;
  const float* Gb = G + (long)b * 10000;

  // gather window + exp (scores |d| < ~4 analytically: max-sub unnecessary).
  // OOB entries: d=0 -> e=1, matching zero-padded x_nei semantics exactly.
  for (int t = tid; t < 1089; t += 256) {
    int dw = t / 33, du = t % 33;
    int i = s + 16 - dw, j = s + 16 - du;
    float v = 0.f;
    if ((unsigned)i < 100u && (unsigned)j < 100u) v = Gb[i * 100 + j];
    dmat[dw][du] = __expf(v);
  }
  __syncthreads();

  // row sums of exp: 4 lanes per row
  if (tid < 132) {
    int row = tid >> 2, g = tid & 3;
    float ssum = 0.f;
    for (int u = g; u < 33; u += 4) ssum += dmat[row][u];
    ssum += __shfl_xor(ssum, 1);
    ssum += __shfl_xor(ssum, 2);
    if (g == 0) rowinv[row] = 1.0f / ssum;
  }
  __syncthreads();

  // alpha: write out + keep in LDS for beta
  float* aout = alpha_out + (long)blk * 1089;
  for (int t = tid; t < 1089; t += 256) {
    int dw = t / 33, du = t % 33;
    float a = dmat[dw][du] * rowinv[dw];
    aout[t] = a;
    dmat[dw][du] = a;
  }
  __syncthreads();

  // beta[u] = sum_w alpha[w][u]: 4 lanes per column
  if (tid < 132) {
    int col = tid >> 2, g = tid & 3;
    float sum = 0.f;
    for (int w = g; w < 33; w += 4) sum += dmat[w][col];
    sum += __shfl_xor(sum, 1);
    sum += __shfl_xor(sum, 2);
    if (g == 0) beta[col] = sum;
  }
  __syncthreads();

  // out[b,s,:] = sum_u beta[u] * vh[b, s+16-u, :]  (2 bf16 per thread via u32)
  const unsigned short* vbase = qkv + (long)(b * 100) * 1536 + 1024;
  {
    float acc0 = 0.f, acc1 = 0.f;
    for (int u = 0; u < 33; ++u) {
      int p = s + 16 - u;
      if ((unsigned)p < 100u) {
        float bw = beta[u];
        u32 pv = *(const u32*)(vbase + (long)p * 1536 + 2 * tid);
        acc0 += bw * bf2f((unsigned short)(pv & 0xFFFFu));
        acc1 += bw * bf2f((unsigned short)(pv >> 16));
      }
    }
    u32 packed = (u32)f2bf(acc0) | ((u32)f2bf(acc1) << 16);
    *(u32*)(outb + (long)blk * 512 + 2 * tid) = packed;
  }
}

extern "C" void kernel_launch(void* const* d_in, const int* in_sizes, int n_in,
                              void* d_out, int out_size, void* d_ws, size_t ws_size,
                              hipStream_t stream) {
  const float* x  = (const float*)d_in[0];
  const float* W0 = (const float*)d_in[1];
  const float* b0 = (const float*)d_in[2];
  const float* Wq = (const float*)d_in[3];
  const float* Wk = (const float*)d_in[4];
  const float* Wv = (const float*)d_in[5];
  const float* W1 = (const float*)d_in[6];
  const float* b1 = (const float*)d_in[7];

  char* ws = (char*)d_ws;
  unsigned short* xb    = (unsigned short*)(ws + 0);         // 6400x256 bf16
  unsigned short* w0t   = (unsigned short*)(ws + 3276800);   // 512x256
  unsigned short* wqkvt = (unsigned short*)(ws + 3538944);   // 1536x512
  unsigned short* w1t   = (unsigned short*)(ws + 5111808);   // 256x512
  unsigned short* h     = (unsigned short*)(ws + 5373952);   // 6400x512
  unsigned short* qkv   = (unsigned short*)(ws + 11927552);  // 6432x1536 (32 pad rows)
  float*          G     = (float*)(ws + 31686656);           // 64x100x100 f32
  unsigned short* outb  = (unsigned short*)(ws + 34246656);  // 6400x512
  // total ws use: 40,800,256 bytes

  float* y_out     = (float*)d_out;            // 6400x256 f32
  float* alpha_out = y_out + 6400 * 256;       // 6400x33x33 f32

  prep_kernel<<<2624, 256, 0, stream>>>(x, W0, Wq, Wk, Wv, W1, xb, w0t, wqkvt, w1t);
  // h = relu(x @ W0 + b0): M=6400, N=512, K=256
  gemm_tile<true,  true ><<<dim3(100, 4),  256, 0, stream>>>(xb, 256, w0t, 256, b0, h, 512, 8);
  // [qh|kh|vh] = h @ [Wq|Wk|Wv]: M=6400, N=1536, K=512
  gemm_tile<false, true ><<<dim3(100, 12), 256, 0, stream>>>(h, 512, wqkvt, 512, nullptr, qkv, 1536, 16);
  // G[b] = qh kh^T / sqrt(512)
  gram_tile<<<dim3(2, 64), 256, 0, stream>>>(qkv, G);
  // softmax windows -> alpha, beta-weighted v -> outb
  attn_kernel<<<6400, 256, 0, stream>>>(G, qkv, alpha_out, outb);
  // y = relu(outb @ W1 + b1): M=6400, N=256, K=512
  gemm_tile<true,  false><<<dim3(100, 2),  256, 0, stream>>>(outb, 512, w1t, 512, b1, y_out, 256, 16);
}